// Round 8
// baseline (569.924 us; speedup 1.0000x reference)
//
#include <hip/hip_runtime.h>
#include <hip/hip_fp16.h>
#include <hip/hip_bf16.h>
#include <stdint.h>

// ---------------------------------------------------------------------------
// ResidualVQ: x (64,512,256) f32, codebooks (6,1024,512) f32
// outputs: quantized_out (64,512,256), indices (64,256,6) as f32,
//          mean_loss, mean_perplexity   -> d_out flat f32, 8486914 elems
//
// R7: R6's fusion (refine of stage q-1 as prologue of gemm q) had two
// intra-dispatch races among the 4 duplicate blocks per tm:
//   (1) r was read-modify-written in place -> slow dup could read a row a
//       fast dup already updated (double subtraction);
//   (2) cand was read (stage q-1 keys) and rewritten (stage q keys) in the
//       same dispatch.
// Fix: ping-pong. r^(q) lives in parity-q%2 buffer: even -> ws R0, odd ->
// d_out[0..8388608) used as scratch (fully overwritten by final_kernel;
// disjoint from idx/scalar output regions). cand ping-pongs 2x2MB. All
// prologue reads are previous-dispatch data => duplicates compute identical
// results => identical concurrent writes are benign. Own-block rbf
// visibility: vmcnt drain at __syncthreads + sc0 A staging loads.
// Prologue prefetches next row's r/cand to hide load latency.
// ---------------------------------------------------------------------------

#define NTROWS 16384
#define DDIM   512
#define CCODES 1024
#define QSTAGE 6

// ws layout (bytes)
#define OFF_R0     ((size_t)0)           // fp32 residual (even stages) 33554432
#define OFF_RBF    ((size_t)33554432)    // bf16 residual  NT*D*2 = 16777216
#define OFF_CBBF   ((size_t)50331648)    // bf16 codebooks = 6291456
#define OFF_CAND0  ((size_t)56623104)    // u32 cand parity0, 2097152
#define OFF_CAND1  ((size_t)58720256)    // u32 cand parity1, 2097152
#define OFF_CBSQ   ((size_t)60817408)    // f32 |c|^2, 6*1024*4
#define OFF_HIST   ((size_t)60841984)    // u32 hist, 6*1024*4
#define OFF_LOSS   ((size_t)60866560)    // f32 loss bins, 6*256*4
#define WS_END     ((size_t)60872704)

#define OUT_IDX_OFF  ((size_t)8388608)
#define OUT_SCAL_OFF ((size_t)8486912)

#define MARGIN 2.0f

typedef __attribute__((ext_vector_type(8))) short short8;
typedef __attribute__((ext_vector_type(8))) unsigned short ushort8v;
typedef __attribute__((ext_vector_type(4))) float f32x4;

__device__ __forceinline__ unsigned short f2bf(float f) {
    uint32_t u = __float_as_uint(f);
    uint32_t r = (u + 0x7fffu + ((u >> 16) & 1u)) >> 16;   // RNE
    return (unsigned short)r;
}
__device__ __forceinline__ uint32_t fkey(float f) {        // order-preserving f32->u32
    uint32_t u = __float_as_uint(f);
    return u ^ ((uint32_t)((int32_t)u >> 31) | 0x80000000u);
}
__device__ __forceinline__ float funkey(uint32_t k) {
    uint32_t u = (k & 0x80000000u) ? (k ^ 0x80000000u) : ~k;
    return __uint_as_float(u);
}
__device__ __forceinline__ uint32_t umin32(uint32_t a, uint32_t b) { return a < b ? a : b; }
__device__ __forceinline__ uint32_t umax32(uint32_t a, uint32_t b) { return a > b ? a : b; }
__device__ __forceinline__ float wave_sum(float v) {
    for (int m = 32; m; m >>= 1) v += __shfl_xor(v, m, 64);
    return v;
}
__device__ __forceinline__ uint32_t wave_min_u32(uint32_t v) {
    for (int m = 32; m; m >>= 1) v = umin32(v, (uint32_t)__shfl_xor((int)v, m, 64));
    return v;
}
template <int AUX>
__device__ __forceinline__ void async_load16(const void* g, void* l) {
    __builtin_amdgcn_global_load_lds(
        (__attribute__((address_space(1))) void*)(void*)g,
        (__attribute__((address_space(3))) void*)l, 16, 0, AUX);
}

// refine core for one row, with r/cand preloaded (ra,rb,key).
// Reads only stable (previous-dispatch) data; writes r_out (+ rbf if
// write_bf). Side effects (idx/hist/loss) only if do_side.
__device__ __forceinline__ void refine_core(
    int nt, int lane, float4 ra, float4 rb, uint32_t key,
    float* r_out, unsigned short* rbf,
    const float* cbq, const float* cbsqq,
    float* out_idx, unsigned int* histq, float* loss_bins,
    int q, int write_bf, int do_side)
{
    float s = ra.x * ra.x + ra.y * ra.y + ra.z * ra.z + ra.w * ra.w
            + rb.x * rb.x + rb.y * rb.y + rb.z * rb.z + rb.w * rb.w;
    const float sumx = wave_sum(s);

    const uint32_t kmin = wave_min_u32(key);
    const float thr = funkey(kmin & ~1023u) + MARGIN;
    unsigned long long mask = __ballot(lane < 32 && funkey(key & ~1023u) <= thr);

    float best = 1e30f;
    int bestc = CCODES;
    while (mask) {
        const int src = __ffsll(mask) - 1;
        mask &= mask - 1;
        const int cc = __shfl((int)(key & 1023u), src, 64);
        const float4* crow = (const float4*)(cbq + (size_t)cc * DDIM);
        float4 ca = crow[lane * 2], cb2 = crow[lane * 2 + 1];
        float dot = ra.x * ca.x + ra.y * ca.y + ra.z * ca.z + ra.w * ca.w
                  + rb.x * cb2.x + rb.y * cb2.y + rb.z * cb2.z + rb.w * cb2.w;
        dot = wave_sum(dot);
        const float de = (sumx - 2.0f * dot) + cbsqq[cc];
        if (de < best || (de == best && cc < bestc)) { best = de; bestc = cc; }
    }

    const float4* cbest = (const float4*)(cbq + (size_t)bestc * DDIM);
    float4 ba = cbest[lane * 2], bb = cbest[lane * 2 + 1];
    float4 na = make_float4(ra.x - ba.x, ra.y - ba.y, ra.z - ba.z, ra.w - ba.w);
    float4 nb = make_float4(rb.x - bb.x, rb.y - bb.y, rb.z - bb.z, rb.w - bb.w);
    float4* rw = (float4*)(r_out + (size_t)nt * DDIM);
    rw[lane * 2] = na; rw[lane * 2 + 1] = nb;
    if (write_bf) {
        ushort8v pk;
        pk[0] = f2bf(na.x); pk[1] = f2bf(na.y); pk[2] = f2bf(na.z); pk[3] = f2bf(na.w);
        pk[4] = f2bf(nb.x); pk[5] = f2bf(nb.y); pk[6] = f2bf(nb.z); pk[7] = f2bf(nb.w);
        *(ushort8v*)(rbf + (size_t)nt * DDIM + lane * 8) = pk;
    }
    if (do_side && lane == 0) {
        out_idx[(size_t)nt * QSTAGE + q] = (float)bestc;
        atomicAdd(&histq[bestc], 1u);
        atomicAdd(&loss_bins[q * 256 + (nt & 255)], best);
    }
}

// --------------------------------------------------------------------------
// prep: blocks [0,1536): bf16 codebooks + |c|^2 (+ zero hist/loss in blk 0)
//       blocks [1536,9728): transpose x (N,D,T) -> r0 (NT,D) fp32+bf16
// --------------------------------------------------------------------------
__global__ __launch_bounds__(256) void prep_kernel(
    const float* __restrict__ x, const float* __restrict__ cb,
    float* __restrict__ r, unsigned short* __restrict__ rbf,
    unsigned short* __restrict__ cbbf, float* __restrict__ cbsq,
    unsigned int* __restrict__ hist, float* __restrict__ loss_bins)
{
    __shared__ float tile[32][33];
    if (blockIdx.x < 1536) {
        const int wave = threadIdx.x >> 6, lane = threadIdx.x & 63;
        const int row = blockIdx.x * 4 + wave;            // 0..6143
        const float* p = cb + (size_t)row * DDIM;
        unsigned short* pb = cbbf + (size_t)row * DDIM;
        float s = 0.f;
#pragma unroll
        for (int t = 0; t < 8; ++t) {
            float v = p[lane + 64 * t];
            pb[lane + 64 * t] = f2bf(v);
            s += v * v;
        }
        s = wave_sum(s);
        if (lane == 0) cbsq[row] = s;
        if (blockIdx.x == 0) {
            for (int i = threadIdx.x; i < QSTAGE * CCODES; i += 256) hist[i] = 0u;
            for (int i = threadIdx.x; i < QSTAGE * 256; i += 256) loss_bins[i] = 0.f;
        }
    } else {
        const int bidx = blockIdx.x - 1536;               // 0..8191
        const int d0 = (bidx & 15) * 32;
        const int t0 = ((bidx >> 4) & 7) * 32;
        const int n  = bidx >> 7;
        const int tx = threadIdx.x & 31, ty = threadIdx.x >> 5;
        const float* xp = x + (size_t)n * (DDIM * 256);
#pragma unroll
        for (int s = 0; s < 4; ++s) {
            int dd = ty + s * 8;
            tile[dd][tx] = xp[(size_t)(d0 + dd) * 256 + t0 + tx];
        }
        __syncthreads();
#pragma unroll
        for (int s = 0; s < 4; ++s) {
            int tt = ty + s * 8;
            float v = tile[tx][tt];
            size_t off = (size_t)(n * 256 + t0 + tt) * DDIM + d0 + tx;
            r[off] = v;
            rbf[off] = f2bf(v);
        }
    }
}

// --------------------------------------------------------------------------
// fused: [optional refine prologue for stage q-1 on own 128 rows, reading
// r_in/cand_in (prev dispatch), writing r_out/rbf] + GEMM of stage q
// (128x256 tile, bf16 MFMA, packed-u32 top-2 -> cand_out).
// grid (128, 4) x 256 : tm = blockIdx.x (XCD swizzle), tn2 = blockIdx.y
// --------------------------------------------------------------------------
__global__ __launch_bounds__(256, 2) void fused_kernel(
    const float* __restrict__ r_in, float* __restrict__ r_out,
    unsigned short* rbf,                      // bf16 residual (gemm A)
    const unsigned short* __restrict__ Bbf,   // cbbf stage-q slice
    const float* __restrict__ cbsq_g,         // |c|^2 stage-q slice
    const uint32_t* __restrict__ cand_in,     // stage q-1 keys (prev dispatch)
    uint32_t* __restrict__ cand_out,          // stage q keys
    const float* cb_prev, const float* cbsq_prev,
    float* out_idx, unsigned int* hist_prev, float* loss_bins,
    int q_prev, int do_refine)
{
    __shared__ __align__(16) unsigned short lA[128 * 32];
    __shared__ __align__(16) unsigned short lB[256 * 32];
    const int tid = threadIdx.x;
    const int wave = tid >> 6, lane = tid & 63;
    const int quad = lane >> 4, l15 = lane & 15;
    const int tm = blockIdx.x, tn2 = blockIdx.y;
    const int wm = wave & 1, wn = wave >> 1;

    if (do_refine) {
        // refine stage q_prev for this block's 128 rows (duplicated over the
        // 4 tn2 siblings; all read only prev-dispatch data -> identical
        // results -> concurrent identical writes benign). Side effects tn2==0.
        const int do_side = (tn2 == 0);
        int nt = tm * 128 + wave * 32;
        const float4* r4 = (const float4*)(r_in + (size_t)nt * DDIM);
        float4 ra = r4[lane * 2], rb = r4[lane * 2 + 1];
        uint32_t key = (lane < 32) ? cand_in[(size_t)nt * 32 + lane] : 0xFFFFFFFFu;
        for (int rr = 0; rr < 32; ++rr, ++nt) {
            float4 pa = make_float4(0.f, 0.f, 0.f, 0.f), pb = pa;
            uint32_t pkey = 0xFFFFFFFFu;
            if (rr < 31) {   // prefetch next row while candidate loop runs
                const float4* r4n = (const float4*)(r_in + (size_t)(nt + 1) * DDIM);
                pa = r4n[lane * 2]; pb = r4n[lane * 2 + 1];
                if (lane < 32) pkey = cand_in[(size_t)(nt + 1) * 32 + lane];
            }
            refine_core(nt, lane, ra, rb, key, r_out, rbf,
                        cb_prev, cbsq_prev, out_idx, hist_prev, loss_bins,
                        q_prev, 1, do_side);
            ra = pa; rb = pb; key = pkey;
        }
        __threadfence_block();   // drain own stores (rbf) before staging
        __syncthreads();         // vmcnt(0): all 128 rbf rows visible
    }

    f32x4 acc[4][8];
#pragma unroll
    for (int i = 0; i < 4; ++i)
#pragma unroll
        for (int j = 0; j < 8; ++j) acc[i][j] = (f32x4){0.f, 0.f, 0.f, 0.f};

    // staging: wave w owns rows [w*16 + lane>>2] (+64/+128/+192 for B).
    // xor chunk swizzle: lane stages global 16B-chunk (lane&3)^((lane>>3)&3);
    // LDS dest stays linear (lane&3).
    const int srow = wave * 16 + (lane >> 2);
    const int gchunk = (lane & 3) ^ ((lane >> 3) & 3);
    const unsigned short* gA0 = rbf + (size_t)(tm * 128 + srow) * DDIM + gchunk * 8;
    const unsigned short* gA1 = gA0 + 64 * DDIM;
    const unsigned short* gB0 = Bbf + (size_t)(tn2 * 256 + srow) * DDIM + gchunk * 8;
    const unsigned short* gB1 = gB0 + 64 * DDIM;
    const unsigned short* gB2 = gB0 + 128 * DDIM;
    const unsigned short* gB3 = gB0 + 192 * DDIM;
    unsigned short* sA0 = &lA[srow * 32 + (lane & 3) * 8];
    unsigned short* sA1 = &lA[(64 + srow) * 32 + (lane & 3) * 8];
    unsigned short* sB0 = &lB[srow * 32 + (lane & 3) * 8];
    unsigned short* sB1 = &lB[(64 + srow) * 32 + (lane & 3) * 8];
    unsigned short* sB2 = &lB[(128 + srow) * 32 + (lane & 3) * 8];
    unsigned short* sB3 = &lB[(192 + srow) * 32 + (lane & 3) * 8];

    for (int kt = 0; kt < DDIM / 32; ++kt) {
        // A with sc0 (aux=1): bypass L1 (rows just rewritten by prologue)
        async_load16<1>(gA0, sA0); async_load16<1>(gA1, sA1);
        async_load16<0>(gB0, sB0); async_load16<0>(gB1, sB1);
        async_load16<0>(gB2, sB2); async_load16<0>(gB3, sB3);
        gA0 += 32; gA1 += 32; gB0 += 32; gB1 += 32; gB2 += 32; gB3 += 32;
        __syncthreads();   // drains vmcnt before LDS reads
        const int cqa = (quad ^ ((l15 >> 1) & 3)) * 8;   // swizzled chunk addr
        short8 af[4], bfr[8];
#pragma unroll
        for (int i = 0; i < 4; ++i)
            af[i] = *(const short8*)&lA[(wm * 64 + i * 16 + l15) * 32 + cqa];
#pragma unroll
        for (int j = 0; j < 8; ++j)
            bfr[j] = *(const short8*)&lB[(wn * 128 + j * 16 + l15) * 32 + cqa];
#pragma unroll
        for (int i = 0; i < 4; ++i)
#pragma unroll
            for (int j = 0; j < 8; ++j)
                acc[i][j] = __builtin_amdgcn_mfma_f32_16x16x32_bf16(
                    af[i], bfr[j], acc[i][j], 0, 0, 0);
        __syncthreads();   // before next tile overwrites LDS
    }

    // epilogue: C/D layout col=lane&15, row=quad*4+reg (m89-verified).
    // Packed top-2 per row per 64-col group (two groups per wave).
    const int rowbase = tm * 128 + wm * 64 + quad * 4;
    const int colbase = tn2 * 256 + wn * 128 + l15;
    const int gbase = tn2 * 4 + wn * 2;        // 64-col group index base
    float cbs[8];
#pragma unroll
    for (int j = 0; j < 8; ++j) cbs[j] = cbsq_g[colbase + j * 16];
#pragma unroll
    for (int i = 0; i < 4; ++i) {
#pragma unroll
        for (int reg = 0; reg < 4; ++reg) {
            const int row = rowbase + i * 16 + reg;
#pragma unroll
            for (int jh = 0; jh < 2; ++jh) {
                uint32_t k[4];
#pragma unroll
                for (int jj = 0; jj < 4; ++jj) {
                    const int j = jh * 4 + jj;
                    float dv = cbs[j] - 2.0f * acc[i][j][reg];
                    k[jj] = (fkey(dv) & ~1023u) | (uint32_t)(colbase + j * 16);
                }
                uint32_t m01 = umin32(k[0], k[1]), M01 = umax32(k[0], k[1]);
                uint32_t m23 = umin32(k[2], k[3]), M23 = umax32(k[2], k[3]);
                uint32_t k1 = umin32(m01, m23);
                uint32_t k2 = umin32(umax32(m01, m23), umin32(M01, M23));
#pragma unroll
                for (int m = 1; m < 16; m <<= 1) {
                    uint32_t o1 = (uint32_t)__shfl_xor((int)k1, m, 64);
                    uint32_t o2 = (uint32_t)__shfl_xor((int)k2, m, 64);
                    uint32_t n1 = umin32(k1, o1);
                    uint32_t n2 = umin32(umax32(k1, o1), umin32(k2, o2));
                    k1 = n1; k2 = n2;
                }
                if (l15 == 0)
                    *(uint2*)&cand_out[((size_t)row * 16 + gbase + jh) * 2] =
                        make_uint2(k1, k2);
            }
        }
    }
}

// --------------------------------------------------------------------------
// standalone refine (last stage): r_in -> r_out, no rbf write.
// grid 4096 x 256 (wave per row)
// --------------------------------------------------------------------------
__global__ __launch_bounds__(256) void refine_kernel(
    const float* __restrict__ r_in, float* __restrict__ r_out,
    const float* __restrict__ cbq, const float* __restrict__ cbsqq,
    const uint32_t* __restrict__ cand_in,
    float* __restrict__ out_idx, unsigned int* __restrict__ histq,
    float* __restrict__ loss_bins, int q)
{
    const int wave = threadIdx.x >> 6, lane = threadIdx.x & 63;
    const int nt = blockIdx.x * 4 + wave;
    const float4* r4 = (const float4*)(r_in + (size_t)nt * DDIM);
    float4 ra = r4[lane * 2], rb = r4[lane * 2 + 1];
    uint32_t key = (lane < 32) ? cand_in[(size_t)nt * 32 + lane] : 0xFFFFFFFFu;
    refine_core(nt, lane, ra, rb, key, r_out, (unsigned short*)0,
                cbq, cbsqq, out_idx, histq, loss_bins, q, 0, 1);
}

// --------------------------------------------------------------------------
// final: blocks [0,8192): out = x - r_final transposed back to (N,D,T);
//        block 8192: mean commit loss + mean perplexity
// --------------------------------------------------------------------------
__global__ __launch_bounds__(256) void final_kernel(
    const float* __restrict__ x, const float* __restrict__ r,
    float* __restrict__ out,
    const unsigned int* __restrict__ hist, const float* __restrict__ loss_bins,
    float* __restrict__ out2)
{
    __shared__ float tile[32][33];    // [t'][d']
    __shared__ float red[4];
    __shared__ float perp_acc;
    const int tid = threadIdx.x, wave = tid >> 6, lane = tid & 63;

    if (blockIdx.x < 8192) {
        const int bidx = blockIdx.x;
        const int d0 = (bidx & 15) * 32;
        const int t0 = ((bidx >> 4) & 7) * 32;
        const int n  = bidx >> 7;
        const int tx = tid & 31, ty = tid >> 5;
#pragma unroll
        for (int s = 0; s < 4; ++s) {
            int tt = ty + s * 8;
            tile[tt][tx] = r[(size_t)(n * 256 + t0 + tt) * DDIM + d0 + tx];
        }
        __syncthreads();
        const float* xp = x + (size_t)n * (DDIM * 256);
        float* op = out + (size_t)n * (DDIM * 256);
#pragma unroll
        for (int s = 0; s < 4; ++s) {
            int dd = ty + s * 8;
            size_t off = (size_t)(d0 + dd) * 256 + t0 + tx;
            op[off] = xp[off] - tile[tx][dd];
        }
        return;
    }

    // scalars block
    if (tid == 0) perp_acc = 0.f;
    __syncthreads();
    for (int q = 0; q < QSTAGE; ++q) {
        float s = 0.f;
        for (int c = tid; c < CCODES; c += 256) {
            float p = (float)hist[q * CCODES + c] * (1.0f / (float)NTROWS);
            s += p * logf(p + 1e-10f);
        }
        s = wave_sum(s);
        if (lane == 0) red[wave] = s;
        __syncthreads();
        if (tid == 0) {
            float tot = red[0] + red[1] + red[2] + red[3];
            perp_acc += expf(-tot);
        }
        __syncthreads();
    }
    float ls = 0.f;
    for (int i = tid; i < QSTAGE * 256; i += 256) ls += loss_bins[i];
    ls = wave_sum(ls);
    if (lane == 0) red[wave] = ls;
    __syncthreads();
    if (tid == 0) {
        float lsum = red[0] + red[1] + red[2] + red[3];
        out2[0] = (lsum / (float)QSTAGE) / ((float)NTROWS * (float)DDIM);
        out2[1] = perp_acc / (float)QSTAGE;
    }
}

// --------------------------------------------------------------------------
extern "C" void kernel_launch(void* const* d_in, const int* in_sizes, int n_in,
                              void* d_out, int out_size, void* d_ws, size_t ws_size,
                              hipStream_t stream)
{
    const float* x  = (const float*)d_in[0];
    const float* cb = (const float*)d_in[1];
    float* out = (float*)d_out;
    char* ws = (char*)d_ws;

    float*          r_even = (float*)(ws + OFF_R0);
    float*          r_odd  = out;     // d_out[0..8388608) as scratch (odd stages)
    unsigned short* rbf    = (unsigned short*)(ws + OFF_RBF);
    unsigned short* cbbf   = (unsigned short*)(ws + OFF_CBBF);
    uint32_t*       cand0  = (uint32_t*)(ws + OFF_CAND0);
    uint32_t*       cand1  = (uint32_t*)(ws + OFF_CAND1);
    float*          cbsq   = (float*)(ws + OFF_CBSQ);
    unsigned int*   hist   = (unsigned int*)(ws + OFF_HIST);
    float*          lbins  = (float*)(ws + OFF_LOSS);

    prep_kernel<<<9728, 256, 0, stream>>>(x, cb, r_even, rbf, cbbf, cbsq,
                                          hist, lbins);

    for (int q = 0; q < QSTAGE; ++q) {
        const size_t cbo  = (size_t)q * CCODES * DDIM;           // gemm slice
        const int    qp   = (q > 0) ? (q - 1) : 0;
        const size_t cbop = (size_t)qp * CCODES * DDIM;          // refine slice
        // refine qp reads r parity qp%2, writes parity q%2; gemm writes cand[q%2]
        const float* rin  = (qp % 2 == 0) ? r_even : r_odd;
        float*       rout = (q  % 2 == 0) ? r_even : r_odd;
        const uint32_t* cin  = (qp % 2 == 0) ? cand0 : cand1;
        uint32_t*       cout = (q  % 2 == 0) ? cand0 : cand1;
        fused_kernel<<<dim3(128, 4), 256, 0, stream>>>(
            rin, rout, rbf, cbbf + cbo, cbsq + q * CCODES,
            cin, cout,
            cb + cbop, cbsq + qp * CCODES,
            out + OUT_IDX_OFF, hist + qp * CCODES, lbins,
            qp, (q > 0) ? 1 : 0);
    }

    // stage 5 refine: reads r parity 1 (r_odd) + cand[1], writes r_even
    refine_kernel<<<4096, 256, 0, stream>>>(
        r_odd, r_even, cb + (size_t)5 * CCODES * DDIM, cbsq + 5 * CCODES,
        cand1, out + OUT_IDX_OFF, hist + 5 * CCODES, lbins, 5);

    final_kernel<<<8193, 256, 0, stream>>>(x, r_even, out, hist, lbins,
                                           out + OUT_SCAL_OFF);
}